// Round 4
// baseline (1171.552 us; speedup 1.0000x reference)
//
#include <hip/hip_runtime.h>
#include <hip/hip_bf16.h>
#include <stdint.h>

typedef __attribute__((ext_vector_type(8))) short bf16x8;
typedef __attribute__((ext_vector_type(4))) float f32x4;
typedef unsigned short ushort_t;
typedef unsigned int uint_t;

__device__ __forceinline__ unsigned short f2bf(float f) {
  unsigned u = __float_as_uint(f);
  u += 0x7fffu + ((u >> 16) & 1u);
  return (unsigned short)(u >> 16);
}
__device__ __forceinline__ float bf2f(unsigned u16) {
  return __uint_as_float(u16 << 16);
}

__global__ void k_zero(int* __restrict__ p, int n) {
  int i = blockIdx.x * blockDim.x + threadIdx.x;
  if (i < n) p[i] = 0;
}

// ---- weights -> bf16, swizzled [l][nt(4)][kt(16)][kg(4)][col(128)][j(8)]
// maps to W[l][k = kt*32+kg*8+j][n = nt*128+col]
__global__ void k_prep_w(const float* __restrict__ W, ushort_t* __restrict__ Wt, int total) {
  int idx = blockIdx.x * blockDim.x + threadIdx.x;
  if (idx >= total) return;
  int j   = idx & 7;
  int col = (idx >> 3) & 127;
  int kg  = (idx >> 10) & 3;
  int kt  = (idx >> 12) & 15;
  int nt  = (idx >> 16) & 3;
  int l   = idx >> 18;
  int k = kt * 32 + kg * 8 + j;
  int n = nt * 128 + col;
  Wt[idx] = f2bf(W[((size_t)(l * 512 + k)) * 512 + n]);
}

// ---- h = log1p(x) @ expW + expb   (wave per node, grid-stride, 16B stores)
__global__ __launch_bounds__(256) void k_expand(const float* __restrict__ x,
                                                const float* __restrict__ eW,
                                                const float* __restrict__ eb,
                                                ushort_t* __restrict__ h, int N) {
  const int wid = (blockIdx.x * 256 + threadIdx.x) >> 6;
  const int nw = (gridDim.x * 256) >> 6;
  const int l = threadIdx.x & 63;

  float wf[11][8];
  float bias[8];
#pragma unroll
  for (int f = 0; f < 11; ++f) {
    float4 a = *(const float4*)&eW[f * 512 + l * 8];
    float4 b = *(const float4*)&eW[f * 512 + l * 8 + 4];
    wf[f][0] = a.x; wf[f][1] = a.y; wf[f][2] = a.z; wf[f][3] = a.w;
    wf[f][4] = b.x; wf[f][5] = b.y; wf[f][6] = b.z; wf[f][7] = b.w;
  }
  {
    float4 a = *(const float4*)&eb[l * 8];
    float4 b = *(const float4*)&eb[l * 8 + 4];
    bias[0] = a.x; bias[1] = a.y; bias[2] = a.z; bias[3] = a.w;
    bias[4] = b.x; bias[5] = b.y; bias[6] = b.z; bias[7] = b.w;
  }

  for (int n = wid; n < N; n += nw) {
    float xv = (l < 11) ? x[(size_t)n * 11 + l] : 0.f;
    float lx = log1pf(xv);
    float acc[8];
#pragma unroll
    for (int j = 0; j < 8; ++j) acc[j] = bias[j];
#pragma unroll
    for (int f = 0; f < 11; ++f) {
      float c = __shfl(lx, f, 64);
#pragma unroll
      for (int j = 0; j < 8; ++j) acc[j] += c * wf[f][j];
    }
    uint4 pu;
    pu.x = (uint_t)f2bf(acc[0]) | ((uint_t)f2bf(acc[1]) << 16);
    pu.y = (uint_t)f2bf(acc[2]) | ((uint_t)f2bf(acc[3]) << 16);
    pu.z = (uint_t)f2bf(acc[4]) | ((uint_t)f2bf(acc[5]) << 16);
    pu.w = (uint_t)f2bf(acc[6]) | ((uint_t)f2bf(acc[7]) << 16);
    *(uint4*)(h + (size_t)n * 512 + l * 8) = pu;
  }
}

__global__ void k_deg(const int* __restrict__ dst, int* __restrict__ deg, int E) {
  int e = blockIdx.x * blockDim.x + threadIdx.x;
  if (e < E) atomicAdd(&deg[dst[e]], 1);
}

__global__ void k_dinv(const int* __restrict__ deg, float* __restrict__ dinv,
                       float* __restrict__ selfn, int N) {
  int n = blockIdx.x * blockDim.x + threadIdx.x;
  if (n >= N) return;
  float d = (float)deg[n] + 2.0f;
  dinv[n] = rsqrtf(d);
  selfn[n] = 2.0f / d;
}

// ---- 2-level exclusive scan of deg -> off (CSR offsets)
__global__ void k_scan_a(const int* __restrict__ deg, int* __restrict__ off,
                         int* __restrict__ bsum, int N) {
  __shared__ int sd[256];
  int t = threadIdx.x;
  int i0 = blockIdx.x * 1024 + t * 4;
  int d[4];
#pragma unroll
  for (int j = 0; j < 4; ++j) d[j] = (i0 + j < N) ? deg[i0 + j] : 0;
  int ts = d[0] + d[1] + d[2] + d[3];
  sd[t] = ts;
  __syncthreads();
  for (int o = 1; o < 256; o <<= 1) {
    int v = (t >= o) ? sd[t - o] : 0;
    __syncthreads();
    sd[t] += v;
    __syncthreads();
  }
  int incl = sd[t];
  int run = incl - ts;
#pragma unroll
  for (int j = 0; j < 4; ++j) {
    if (i0 + j < N) off[i0 + j] = run;
    run += d[j];
  }
  if (t == 255) bsum[blockIdx.x] = incl;
}

__global__ void k_scan_b(const int* __restrict__ bsum, int* __restrict__ bpre, int nb,
                         int* __restrict__ off, int N, int E) {
  __shared__ int sd[256];
  int t = threadIdx.x;
  int v = (t < nb) ? bsum[t] : 0;
  sd[t] = v;
  __syncthreads();
  for (int o = 1; o < 256; o <<= 1) {
    int u = (t >= o) ? sd[t - o] : 0;
    __syncthreads();
    sd[t] += u;
    __syncthreads();
  }
  if (t < nb) bpre[t] = sd[t] - v;
  if (t == 0) off[N] = E;
}

__global__ void k_scan_c(int* __restrict__ off, const int* __restrict__ bpre, int N) {
  int i = blockIdx.x * blockDim.x + threadIdx.x;
  if (i < N) off[i] += bpre[i >> 10];
}

__global__ void k_fill(const int* __restrict__ src, const int* __restrict__ dst,
                       const int* __restrict__ off, int* __restrict__ cur,
                       int* __restrict__ ssrc, int E) {
  int e = blockIdx.x * blockDim.x + threadIdx.x;
  if (e >= E) return;
  int t = dst[e];
  int p = atomicAdd(&cur[t], 1);
  ssrc[off[t] + p] = src[e];
}

// ---- s = A_hat * h   (gather on h; wave per node, grid-stride)
__global__ __launch_bounds__(256) void k_agg2(const ushort_t* __restrict__ h,
                                              ushort_t* __restrict__ s,
                                              const int* __restrict__ off,
                                              const int* __restrict__ ssrc,
                                              const float* __restrict__ dinv,
                                              const float* __restrict__ selfn, int N) {
  const int wid = (blockIdx.x * 256 + threadIdx.x) >> 6;
  const int nw = (gridDim.x * 256) >> 6;
  const int l = threadIdx.x & 63;

  for (int n = wid; n < N; n += nw) {
    int s0 = off[n], s1 = off[n + 1];
    float dn = dinv[n];
    float sn = selfn[n];
    float acc[8];
    {
      uint4 u = *(const uint4*)(h + (size_t)n * 512 + l * 8);
      acc[0] = sn * bf2f(u.x & 0xffffu); acc[1] = sn * bf2f(u.x >> 16);
      acc[2] = sn * bf2f(u.y & 0xffffu); acc[3] = sn * bf2f(u.y >> 16);
      acc[4] = sn * bf2f(u.z & 0xffffu); acc[5] = sn * bf2f(u.z >> 16);
      acc[6] = sn * bf2f(u.w & 0xffffu); acc[7] = sn * bf2f(u.w >> 16);
    }
    for (int i = s0; i < s1; ++i) {
      int sv = ssrc[i];
      float w = dn * dinv[sv];
      uint4 u = *(const uint4*)(h + (size_t)sv * 512 + l * 8);
      acc[0] += w * bf2f(u.x & 0xffffu); acc[1] += w * bf2f(u.x >> 16);
      acc[2] += w * bf2f(u.y & 0xffffu); acc[3] += w * bf2f(u.y >> 16);
      acc[4] += w * bf2f(u.z & 0xffffu); acc[5] += w * bf2f(u.z >> 16);
      acc[6] += w * bf2f(u.w & 0xffffu); acc[7] += w * bf2f(u.w >> 16);
    }
    uint4 pu;
    pu.x = (uint_t)f2bf(acc[0]) | ((uint_t)f2bf(acc[1]) << 16);
    pu.y = (uint_t)f2bf(acc[2]) | ((uint_t)f2bf(acc[3]) << 16);
    pu.z = (uint_t)f2bf(acc[4]) | ((uint_t)f2bf(acc[5]) << 16);
    pu.w = (uint_t)f2bf(acc[6]) | ((uint_t)f2bf(acc[7]) << 16);
    *(uint4*)(s + (size_t)n * 512 + l * 8) = pu;
  }
}

// ---- h += relu(s @ W[l] + b)  (bf16 MFMA, 128x128 tile, fused epilogue)
__global__ __launch_bounds__(256) void k_gemm(const ushort_t* __restrict__ s,
                                              const ushort_t* __restrict__ Wt,
                                              const float* __restrict__ gbl,
                                              ushort_t* __restrict__ h, int N) {
  __shared__ alignas(16) short Alds[4 * 128 * 8];  // [kg][row][8]
  __shared__ alignas(16) short Blds[4 * 128 * 8];  // [kg][col][8]
  const int tid = threadIdx.x;
  const int m0 = blockIdx.x * 128;
  const int nt = blockIdx.y;
  const int wv = tid >> 6, ln = tid & 63;
  const int wrow = wv >> 1, wcol = wv & 1;
  const int l15 = ln & 15, l4 = ln >> 4;

  f32x4 acc[4][4];
#pragma unroll
  for (int i = 0; i < 4; ++i)
#pragma unroll
    for (int j = 0; j < 4; ++j) acc[i][j] = (f32x4){0.f, 0.f, 0.f, 0.f};

  const int r = tid >> 1, hh = tid & 1;
  const int grow = m0 + r;
  const bool valid = grow < N;
  const ushort_t* srow = s + (size_t)grow * 512 + hh * 16;
  const int abase0 = ((hh * 2 + 0) * 128 + r) * 8;
  const int abase1 = ((hh * 2 + 1) * 128 + r) * 8;

  for (int kt = 0; kt < 16; ++kt) {
    __syncthreads();
    // B stage: 8KB linear global_load_lds (Wt pre-swizzled to LDS layout)
    {
      const ushort_t* wt = Wt + (((size_t)nt * 16 + kt) << 12);
      const ushort_t* g1 = wt + ((wv * 64 + ln) << 3);
      const ushort_t* g2 = g1 + 2048;
      __builtin_amdgcn_global_load_lds(
          (const __attribute__((address_space(1))) unsigned int*)g1,
          (__attribute__((address_space(3))) unsigned int*)&Blds[(wv * 64) << 3], 16, 0, 0);
      __builtin_amdgcn_global_load_lds(
          (const __attribute__((address_space(1))) unsigned int*)g2,
          (__attribute__((address_space(3))) unsigned int*)&Blds[(256 + wv * 64) << 3], 16, 0, 0);
    }
    // A stage: 16 bf16 k-values, ds_write
    {
      bf16x8 v0, v1;
      if (valid) {
        v0 = ((const bf16x8*)(srow + kt * 32))[0];
        v1 = ((const bf16x8*)(srow + kt * 32))[1];
      } else {
        v0 = (bf16x8){0, 0, 0, 0, 0, 0, 0, 0};
        v1 = v0;
      }
      *(bf16x8*)&Alds[abase0] = v0;
      *(bf16x8*)&Alds[abase1] = v1;
    }
    __syncthreads();
    bf16x8 a[4], b[4];
#pragma unroll
    for (int i = 0; i < 4; ++i) {
      a[i] = *(const bf16x8*)&Alds[(l4 * 128 + wrow * 64 + i * 16 + l15) * 8];
      b[i] = *(const bf16x8*)&Blds[(l4 * 128 + wcol * 64 + i * 16 + l15) * 8];
    }
#pragma unroll
    for (int i = 0; i < 4; ++i)
#pragma unroll
      for (int j = 0; j < 4; ++j)
        acc[i][j] = __builtin_amdgcn_mfma_f32_16x16x32_bf16(a[i], b[j], acc[i][j], 0, 0, 0);
  }

  // epilogue: h[row,col] += relu(acc + bias[col])
  float bj[4];
#pragma unroll
  for (int j = 0; j < 4; ++j)
    bj[j] = gbl[nt * 128 + wcol * 64 + j * 16 + l15];

#pragma unroll
  for (int i = 0; i < 4; ++i) {
    int row0 = m0 + wrow * 64 + i * 16 + l4 * 4;
#pragma unroll
    for (int v = 0; v < 4; ++v) {
      int row = row0 + v;
      if (row < N) {
#pragma unroll
        for (int j = 0; j < 4; ++j) {
          int col = nt * 128 + wcol * 64 + j * 16 + l15;
          size_t idx = (size_t)row * 512 + col;
          float hv = bf2f(h[idx]);
          hv += fmaxf(acc[i][j][v] + bj[j], 0.f);
          h[idx] = f2bf(hv);
        }
      }
    }
  }
}

__device__ __forceinline__ int lbound(const int* a, int n, int v) {
  int lo = 0, hi = n;
  while (lo < hi) {
    int m = (lo + hi) >> 1;
    if (a[m] < v) lo = m + 1; else hi = m;
  }
  return lo;
}

// ---- global_add_pool: block per graph, 16B loads, 4-way row parallel + LDS reduce
__global__ __launch_bounds__(256) void k_pool(const ushort_t* __restrict__ h,
                                              const int* __restrict__ batch,
                                              float* __restrict__ out, int N) {
  __shared__ float red[4 * 512];
  int g = blockIdx.x;
  int t = threadIdx.x;
  int w = t >> 6, l = t & 63;
  int start = lbound(batch, N, g);
  int end = lbound(batch, N, g + 1);
  float acc[8];
#pragma unroll
  for (int j = 0; j < 8; ++j) acc[j] = 0.f;
  for (int n = start + w; n < end; n += 4) {
    uint4 u = *(const uint4*)(h + (size_t)n * 512 + l * 8);
    acc[0] += bf2f(u.x & 0xffffu); acc[1] += bf2f(u.x >> 16);
    acc[2] += bf2f(u.y & 0xffffu); acc[3] += bf2f(u.y >> 16);
    acc[4] += bf2f(u.z & 0xffffu); acc[5] += bf2f(u.z >> 16);
    acc[6] += bf2f(u.w & 0xffffu); acc[7] += bf2f(u.w >> 16);
  }
#pragma unroll
  for (int j = 0; j < 8; ++j) red[w * 512 + l * 8 + j] = acc[j];
  __syncthreads();
  if (t < 128) {
    float4 sv = make_float4(0.f, 0.f, 0.f, 0.f);
#pragma unroll
    for (int ww = 0; ww < 4; ++ww) {
      float4 v = *(const float4*)&red[ww * 512 + t * 4];
      sv.x += v.x; sv.y += v.y; sv.z += v.z; sv.w += v.w;
    }
    *(float4*)&out[(size_t)g * 512 + t * 4] = sv;
  }
}

extern "C" void kernel_launch(void* const* d_in, const int* in_sizes, int n_in,
                              void* d_out, int out_size, void* d_ws, size_t ws_size,
                              hipStream_t stream) {
  const float* x  = (const float*)d_in[0];
  const int* ei   = (const int*)d_in[1];
  const int* batch= (const int*)d_in[2];
  const float* eW = (const float*)d_in[3];
  const float* eb = (const float*)d_in[4];
  const float* gW = (const float*)d_in[5];
  const float* gb = (const float*)d_in[6];
  float* out = (float*)d_out;

  const int N = in_sizes[0] / 11;
  const int E = in_sizes[1] / 2;
  const int G = out_size / 512;
  const int L = in_sizes[5] / (512 * 512);

  const int* src = ei;
  const int* dst = ei + E;

  size_t nd = (size_t)N * 512;
  char* p = (char*)d_ws;
  auto carve = [&](size_t bytes) {
    char* q = p;
    p += (bytes + 255) & ~(size_t)255;
    return q;
  };
  ushort_t* h         = (ushort_t*)carve(nd * 2);
  ushort_t* s         = (ushort_t*)carve(nd * 2);
  ushort_t* Wt        = (ushort_t*)carve((size_t)L * 512 * 512 * 2);
  int* deg            = (int*)carve((size_t)N * 4);
  float* dinv         = (float*)carve((size_t)N * 4);
  float* selfn        = (float*)carve((size_t)N * 4);
  int* off            = (int*)carve(((size_t)N + 1) * 4);
  int* cur            = (int*)carve((size_t)N * 4);
  int* ssrc           = (int*)carve((size_t)E * 4);
  int* bsum           = (int*)carve(1024);
  int* bpre           = (int*)carve(1024);

  k_zero<<<(N + 255) / 256, 256, 0, stream>>>(deg, N);
  k_zero<<<(N + 255) / 256, 256, 0, stream>>>(cur, N);

  int totW = L * 512 * 512;
  k_prep_w<<<(totW + 255) / 256, 256, 0, stream>>>(gW, Wt, totW);
  k_expand<<<2048, 256, 0, stream>>>(x, eW, eb, h, N);
  k_deg<<<(E + 255) / 256, 256, 0, stream>>>(dst, deg, E);
  k_dinv<<<(N + 255) / 256, 256, 0, stream>>>(deg, dinv, selfn, N);
  int nb = (N + 1023) / 1024;
  k_scan_a<<<nb, 256, 0, stream>>>(deg, off, bsum, N);
  k_scan_b<<<1, 256, 0, stream>>>(bsum, bpre, nb, off, N, E);
  k_scan_c<<<(N + 255) / 256, 256, 0, stream>>>(off, bpre, N);
  k_fill<<<(E + 255) / 256, 256, 0, stream>>>(src, dst, off, cur, ssrc, E);

  dim3 ggrid((N + 127) / 128, 4);
  for (int l = 0; l < L; ++l) {
    k_agg2<<<2048, 256, 0, stream>>>(h, s, off, ssrc, dinv, selfn, N);
    k_gemm<<<ggrid, 256, 0, stream>>>(s, Wt + (size_t)l * 512 * 512,
                                      gb + (size_t)l * 512, h, N);
  }
  k_pool<<<G, 256, 0, stream>>>(h, batch, out, N);
}

// Round 5
// 1124.375 us; speedup vs baseline: 1.0420x; 1.0420x over previous
//
#include <hip/hip_runtime.h>
#include <hip/hip_bf16.h>
#include <stdint.h>

typedef __attribute__((ext_vector_type(8))) short bf16x8;
typedef __attribute__((ext_vector_type(4))) float f32x4;
typedef unsigned short ushort_t;
typedef unsigned int uint_t;

__device__ __forceinline__ unsigned short f2bf(float f) {
  unsigned u = __float_as_uint(f);
  u += 0x7fffu + ((u >> 16) & 1u);
  return (unsigned short)(u >> 16);
}
__device__ __forceinline__ float bf2f(unsigned u16) {
  return __uint_as_float(u16 << 16);
}
__device__ __forceinline__ void fma8(float* a, uint4 u, float w) {
  a[0] += w * bf2f(u.x & 0xffffu); a[1] += w * bf2f(u.x >> 16);
  a[2] += w * bf2f(u.y & 0xffffu); a[3] += w * bf2f(u.y >> 16);
  a[4] += w * bf2f(u.z & 0xffffu); a[5] += w * bf2f(u.z >> 16);
  a[6] += w * bf2f(u.w & 0xffffu); a[7] += w * bf2f(u.w >> 16);
}
__device__ __forceinline__ bf16x8 pack8(const float* a) {
  union { bf16x8 v; ushort_t s[8]; } u;
#pragma unroll
  for (int j = 0; j < 8; ++j) u.s[j] = f2bf(a[j]);
  return u.v;
}

__global__ void k_zero(int* __restrict__ p, int n) {
  int i = blockIdx.x * blockDim.x + threadIdx.x;
  if (i < n) p[i] = 0;
}

// ---- weights -> bf16, layout [l][kt(16)][kg(4)][col(512)][j(8)]
// value = W[l][k = kt*32 + kg*8 + j][n = col]
__global__ void k_prep_w(const float* __restrict__ W, ushort_t* __restrict__ Wt, int total) {
  int idx = blockIdx.x * blockDim.x + threadIdx.x;
  if (idx >= total) return;
  int j   = idx & 7;
  int col = (idx >> 3) & 511;
  int kg  = (idx >> 12) & 3;
  int kt  = (idx >> 14) & 15;
  int l   = idx >> 18;
  int k = kt * 32 + kg * 8 + j;
  Wt[idx] = f2bf(W[((size_t)(l * 512 + k)) * 512 + col]);
}

// ---- h = log1p(x) @ expW + expb   (wave per node, grid-stride, 16B stores)
__global__ __launch_bounds__(256) void k_expand(const float* __restrict__ x,
                                                const float* __restrict__ eW,
                                                const float* __restrict__ eb,
                                                ushort_t* __restrict__ h, int N) {
  const int wid = (blockIdx.x * 256 + threadIdx.x) >> 6;
  const int nw = (gridDim.x * 256) >> 6;
  const int l = threadIdx.x & 63;

  float wf[11][8];
  float bias[8];
#pragma unroll
  for (int f = 0; f < 11; ++f) {
    float4 a = *(const float4*)&eW[f * 512 + l * 8];
    float4 b = *(const float4*)&eW[f * 512 + l * 8 + 4];
    wf[f][0] = a.x; wf[f][1] = a.y; wf[f][2] = a.z; wf[f][3] = a.w;
    wf[f][4] = b.x; wf[f][5] = b.y; wf[f][6] = b.z; wf[f][7] = b.w;
  }
  {
    float4 a = *(const float4*)&eb[l * 8];
    float4 b = *(const float4*)&eb[l * 8 + 4];
    bias[0] = a.x; bias[1] = a.y; bias[2] = a.z; bias[3] = a.w;
    bias[4] = b.x; bias[5] = b.y; bias[6] = b.z; bias[7] = b.w;
  }

  for (int n = wid; n < N; n += nw) {
    float xv = (l < 11) ? x[(size_t)n * 11 + l] : 0.f;
    float lx = log1pf(xv);
    float acc[8];
#pragma unroll
    for (int j = 0; j < 8; ++j) acc[j] = bias[j];
#pragma unroll
    for (int f = 0; f < 11; ++f) {
      float c = __shfl(lx, f, 64);
#pragma unroll
      for (int j = 0; j < 8; ++j) acc[j] += c * wf[f][j];
    }
    uint4 pu;
    pu.x = (uint_t)f2bf(acc[0]) | ((uint_t)f2bf(acc[1]) << 16);
    pu.y = (uint_t)f2bf(acc[2]) | ((uint_t)f2bf(acc[3]) << 16);
    pu.z = (uint_t)f2bf(acc[4]) | ((uint_t)f2bf(acc[5]) << 16);
    pu.w = (uint_t)f2bf(acc[6]) | ((uint_t)f2bf(acc[7]) << 16);
    *(uint4*)(h + (size_t)n * 512 + l * 8) = pu;
  }
}

__global__ void k_deg(const int* __restrict__ dst, int* __restrict__ deg, int E) {
  int e = blockIdx.x * blockDim.x + threadIdx.x;
  if (e < E) atomicAdd(&deg[dst[e]], 1);
}

__global__ void k_dinv(const int* __restrict__ deg, float* __restrict__ dinv,
                       float* __restrict__ selfn, int N) {
  int n = blockIdx.x * blockDim.x + threadIdx.x;
  if (n >= N) return;
  float d = (float)deg[n] + 2.0f;
  dinv[n] = rsqrtf(d);
  selfn[n] = 2.0f / d;
}

// ---- 2-level exclusive scan of deg -> off (CSR offsets)
__global__ void k_scan_a(const int* __restrict__ deg, int* __restrict__ off,
                         int* __restrict__ bsum, int N) {
  __shared__ int sd[256];
  int t = threadIdx.x;
  int i0 = blockIdx.x * 1024 + t * 4;
  int d[4];
#pragma unroll
  for (int j = 0; j < 4; ++j) d[j] = (i0 + j < N) ? deg[i0 + j] : 0;
  int ts = d[0] + d[1] + d[2] + d[3];
  sd[t] = ts;
  __syncthreads();
  for (int o = 1; o < 256; o <<= 1) {
    int v = (t >= o) ? sd[t - o] : 0;
    __syncthreads();
    sd[t] += v;
    __syncthreads();
  }
  int incl = sd[t];
  int run = incl - ts;
#pragma unroll
  for (int j = 0; j < 4; ++j) {
    if (i0 + j < N) off[i0 + j] = run;
    run += d[j];
  }
  if (t == 255) bsum[blockIdx.x] = incl;
}

__global__ void k_scan_b(const int* __restrict__ bsum, int* __restrict__ bpre, int nb,
                         int* __restrict__ off, int N, int E) {
  __shared__ int sd[256];
  int t = threadIdx.x;
  int v = (t < nb) ? bsum[t] : 0;
  sd[t] = v;
  __syncthreads();
  for (int o = 1; o < 256; o <<= 1) {
    int u = (t >= o) ? sd[t - o] : 0;
    __syncthreads();
    sd[t] += u;
    __syncthreads();
  }
  if (t < nb) bpre[t] = sd[t] - v;
  if (t == 0) off[N] = E;
}

__global__ void k_scan_c(int* __restrict__ off, const int* __restrict__ bpre, int N) {
  int i = blockIdx.x * blockDim.x + threadIdx.x;
  if (i < N) off[i] += bpre[i >> 10];
}

__global__ void k_fill(const int* __restrict__ src, const int* __restrict__ dst,
                       const int* __restrict__ off, int* __restrict__ cur,
                       int* __restrict__ ssrc, int E) {
  int e = blockIdx.x * blockDim.x + threadIdx.x;
  if (e >= E) return;
  int t = dst[e];
  int p = atomicAdd(&cur[t], 1);
  ssrc[off[t] + p] = src[e];
}

// ---- fused layer: h_out = h_in + relu((A_hat h_in) W + b)
// block: 64 rows x 512 cols, 1024 threads (16 waves), 128KB LDS
__global__ __launch_bounds__(1024, 4) void k_fused(const ushort_t* __restrict__ hin,
                                                   ushort_t* __restrict__ hout,
                                                   const ushort_t* __restrict__ Wt,
                                                   const float* __restrict__ gbl,
                                                   const int* __restrict__ off,
                                                   const int* __restrict__ ssrc,
                                                   const float* __restrict__ dinv,
                                                   const float* __restrict__ selfn, int N) {
  __shared__ alignas(16) ushort_t s_tile[64 * 512];   // 64KB, XOR-swizzled rows
  __shared__ alignas(16) ushort_t Bbuf[2][16384];     // 2 x 32KB [kg4][col512][j8]
  const int t = threadIdx.x;
  const int wv = t >> 6, ln = t & 63;
  const int bm0 = blockIdx.x * 64;

  // prefetch B tile kt=0 (linear global_load_lds, 16B/lane)
  {
    const ushort_t* src = Wt + wv * 1024 + ln * 8;
    __builtin_amdgcn_global_load_lds(
        (const __attribute__((address_space(1))) uint_t*)src,
        (__attribute__((address_space(3))) uint_t*)&Bbuf[0][wv * 1024], 16, 0, 0);
    __builtin_amdgcn_global_load_lds(
        (const __attribute__((address_space(1))) uint_t*)(src + 512),
        (__attribute__((address_space(3))) uint_t*)&Bbuf[0][wv * 1024 + 512], 16, 0, 0);
  }

  // ---- gather phase: wave wv owns rows wv*4 .. wv*4+3, dual-row interleave
#pragma unroll
  for (int pr = 0; pr < 2; ++pr) {
    int r0l = wv * 4 + pr * 2, r1l = r0l + 1;
    int r0 = bm0 + r0l, r1 = bm0 + r1l;
    bool v0 = r0 < N, v1 = r1 < N;
    float a0[8], a1[8];
#pragma unroll
    for (int j = 0; j < 8; ++j) { a0[j] = 0.f; a1[j] = 0.f; }
    int i0 = 0, e0 = 0, i1 = 0, e1 = 0;
    float dn0 = 0.f, dn1 = 0.f;
    if (v0) {
      i0 = off[r0]; e0 = off[r0 + 1]; dn0 = dinv[r0];
      uint4 u = *(const uint4*)(hin + (size_t)r0 * 512 + ln * 8);
      fma8(a0, u, selfn[r0]);
    }
    if (v1) {
      i1 = off[r1]; e1 = off[r1 + 1]; dn1 = dinv[r1];
      uint4 u = *(const uint4*)(hin + (size_t)r1 * 512 + ln * 8);
      fma8(a1, u, selfn[r1]);
    }
    while (i0 < e0 && i1 < e1) {
      int n0 = ssrc[i0++], n1 = ssrc[i1++];
      float w0 = dn0 * dinv[n0], w1 = dn1 * dinv[n1];
      uint4 u0 = *(const uint4*)(hin + (size_t)n0 * 512 + ln * 8);
      uint4 u1 = *(const uint4*)(hin + (size_t)n1 * 512 + ln * 8);
      fma8(a0, u0, w0);
      fma8(a1, u1, w1);
    }
    while (i0 < e0) {
      int n0 = ssrc[i0++];
      float w0 = dn0 * dinv[n0];
      uint4 u0 = *(const uint4*)(hin + (size_t)n0 * 512 + ln * 8);
      fma8(a0, u0, w0);
    }
    while (i1 < e1) {
      int n1 = ssrc[i1++];
      float w1 = dn1 * dinv[n1];
      uint4 u1 = *(const uint4*)(hin + (size_t)n1 * 512 + ln * 8);
      fma8(a1, u1, w1);
    }
    // swizzled LDS write: byte = row*1024 + ((ln*16) ^ ((row&7)<<4))
    *(bf16x8*)((char*)s_tile + r0l * 1024 + ((ln * 16) ^ ((r0l & 7) << 4))) = pack8(a0);
    *(bf16x8*)((char*)s_tile + r1l * 1024 + ((ln * 16) ^ ((r1l & 7) << 4))) = pack8(a1);
  }
  __syncthreads();  // s_tile + B[0] ready

  // ---- MFMA phase: wave -> 32x64 output (wrow = wv>>3, wcol = wv&7)
  const int wrow = wv >> 3, wcol = wv & 7;
  const int l15 = ln & 15, l4 = ln >> 4;
  f32x4 acc[2][4];
#pragma unroll
  for (int i = 0; i < 2; ++i)
#pragma unroll
    for (int j = 0; j < 4; ++j) acc[i][j] = (f32x4){0.f, 0.f, 0.f, 0.f};

  for (int kt = 0; kt < 16; ++kt) {
    const int cur = kt & 1;
    if (kt < 15) {
      const ushort_t* src = Wt + (kt + 1) * 16384 + wv * 1024 + ln * 8;
      __builtin_amdgcn_global_load_lds(
          (const __attribute__((address_space(1))) uint_t*)src,
          (__attribute__((address_space(3))) uint_t*)&Bbuf[cur ^ 1][wv * 1024], 16, 0, 0);
      __builtin_amdgcn_global_load_lds(
          (const __attribute__((address_space(1))) uint_t*)(src + 512),
          (__attribute__((address_space(3))) uint_t*)&Bbuf[cur ^ 1][wv * 1024 + 512], 16, 0, 0);
    }
    bf16x8 a[2], b[4];
#pragma unroll
    for (int i = 0; i < 2; ++i) {
      int row = wrow * 32 + i * 16 + l15;
      a[i] = *(const bf16x8*)((const char*)s_tile + row * 1024 +
                              (((kt * 64 + l4 * 16)) ^ ((row & 7) << 4)));
    }
#pragma unroll
    for (int j = 0; j < 4; ++j)
      b[j] = *(const bf16x8*)&Bbuf[cur][l4 * 4096 + (wcol * 64 + j * 16 + l15) * 8];
#pragma unroll
    for (int i = 0; i < 2; ++i)
#pragma unroll
      for (int j = 0; j < 4; ++j)
        acc[i][j] = __builtin_amdgcn_mfma_f32_16x16x32_bf16(a[i], b[j], acc[i][j], 0, 0, 0);
    __syncthreads();
  }

  // ---- epilogue: stage f32 C through freed Bbuf (32 rows x 512 cols per pass)
  float* cst = (float*)&Bbuf[0][0];  // 64KB = 32*512 f32
#pragma unroll
  for (int p = 0; p < 2; ++p) {
    if (wrow == p) {
#pragma unroll
      for (int i = 0; i < 2; ++i)
#pragma unroll
        for (int v = 0; v < 4; ++v) {
          int r32 = i * 16 + l4 * 4 + v;
#pragma unroll
          for (int j = 0; j < 4; ++j)
            cst[r32 * 512 + wcol * 64 + j * 16 + l15] = acc[i][j][v];
        }
    }
    __syncthreads();
#pragma unroll
    for (int w = 0; w < 2; ++w) {
      int g = t + w * 1024;
      int row_l = g >> 6, colg = g & 63;
      int grow = bm0 + p * 32 + row_l;
      if (grow < N) {
        float c[8];
        float4 c0 = *(const float4*)&cst[row_l * 512 + colg * 8];
        float4 c1 = *(const float4*)&cst[row_l * 512 + colg * 8 + 4];
        c[0] = c0.x; c[1] = c0.y; c[2] = c0.z; c[3] = c0.w;
        c[4] = c1.x; c[5] = c1.y; c[6] = c1.z; c[7] = c1.w;
        float4 b0 = *(const float4*)&gbl[colg * 8];
        float4 b1 = *(const float4*)&gbl[colg * 8 + 4];
        float bb[8] = {b0.x, b0.y, b0.z, b0.w, b1.x, b1.y, b1.z, b1.w};
        uint4 hu = *(const uint4*)(hin + (size_t)grow * 512 + colg * 8);
        float hv[8];
        hv[0] = bf2f(hu.x & 0xffffu); hv[1] = bf2f(hu.x >> 16);
        hv[2] = bf2f(hu.y & 0xffffu); hv[3] = bf2f(hu.y >> 16);
        hv[4] = bf2f(hu.z & 0xffffu); hv[5] = bf2f(hu.z >> 16);
        hv[6] = bf2f(hu.w & 0xffffu); hv[7] = bf2f(hu.w >> 16);
#pragma unroll
        for (int j = 0; j < 8; ++j) hv[j] += fmaxf(c[j] + bb[j], 0.f);
        uint4 pu;
        pu.x = (uint_t)f2bf(hv[0]) | ((uint_t)f2bf(hv[1]) << 16);
        pu.y = (uint_t)f2bf(hv[2]) | ((uint_t)f2bf(hv[3]) << 16);
        pu.z = (uint_t)f2bf(hv[4]) | ((uint_t)f2bf(hv[5]) << 16);
        pu.w = (uint_t)f2bf(hv[6]) | ((uint_t)f2bf(hv[7]) << 16);
        *(uint4*)(hout + (size_t)grow * 512 + colg * 8) = pu;
      }
    }
    __syncthreads();
  }
}

__device__ __forceinline__ int lbound(const int* a, int n, int v) {
  int lo = 0, hi = n;
  while (lo < hi) {
    int m = (lo + hi) >> 1;
    if (a[m] < v) lo = m + 1; else hi = m;
  }
  return lo;
}

// ---- global_add_pool: block per graph, 16B loads, 4-way row parallel + LDS reduce
__global__ __launch_bounds__(256) void k_pool(const ushort_t* __restrict__ h,
                                              const int* __restrict__ batch,
                                              float* __restrict__ out, int N) {
  __shared__ float red[4 * 512];
  int g = blockIdx.x;
  int t = threadIdx.x;
  int w = t >> 6, l = t & 63;
  int start = lbound(batch, N, g);
  int end = lbound(batch, N, g + 1);
  float acc[8];
#pragma unroll
  for (int j = 0; j < 8; ++j) acc[j] = 0.f;
  for (int n = start + w; n < end; n += 4) {
    uint4 u = *(const uint4*)(h + (size_t)n * 512 + l * 8);
    acc[0] += bf2f(u.x & 0xffffu); acc[1] += bf2f(u.x >> 16);
    acc[2] += bf2f(u.y & 0xffffu); acc[3] += bf2f(u.y >> 16);
    acc[4] += bf2f(u.z & 0xffffu); acc[5] += bf2f(u.z >> 16);
    acc[6] += bf2f(u.w & 0xffffu); acc[7] += bf2f(u.w >> 16);
  }
#pragma unroll
  for (int j = 0; j < 8; ++j) red[w * 512 + l * 8 + j] = acc[j];
  __syncthreads();
  if (t < 128) {
    float4 sv = make_float4(0.f, 0.f, 0.f, 0.f);
#pragma unroll
    for (int ww = 0; ww < 4; ++ww) {
      float4 v = *(const float4*)&red[ww * 512 + t * 4];
      sv.x += v.x; sv.y += v.y; sv.z += v.z; sv.w += v.w;
    }
    *(float4*)&out[(size_t)g * 512 + t * 4] = sv;
  }
}

extern "C" void kernel_launch(void* const* d_in, const int* in_sizes, int n_in,
                              void* d_out, int out_size, void* d_ws, size_t ws_size,
                              hipStream_t stream) {
  const float* x  = (const float*)d_in[0];
  const int* ei   = (const int*)d_in[1];
  const int* batch= (const int*)d_in[2];
  const float* eW = (const float*)d_in[3];
  const float* eb = (const float*)d_in[4];
  const float* gW = (const float*)d_in[5];
  const float* gb = (const float*)d_in[6];
  float* out = (float*)d_out;

  const int N = in_sizes[0] / 11;
  const int E = in_sizes[1] / 2;
  const int G = out_size / 512;
  const int L = in_sizes[5] / (512 * 512);

  const int* src = ei;
  const int* dst = ei + E;

  size_t nd = (size_t)N * 512;
  char* p = (char*)d_ws;
  auto carve = [&](size_t bytes) {
    char* q = p;
    p += (bytes + 255) & ~(size_t)255;
    return q;
  };
  ushort_t* h0        = (ushort_t*)carve(nd * 2);
  ushort_t* h1        = (ushort_t*)carve(nd * 2);
  ushort_t* Wt        = (ushort_t*)carve((size_t)L * 512 * 512 * 2);
  int* deg            = (int*)carve((size_t)N * 4);
  float* dinv         = (float*)carve((size_t)N * 4);
  float* selfn        = (float*)carve((size_t)N * 4);
  int* off            = (int*)carve(((size_t)N + 1) * 4);
  int* cur            = (int*)carve((size_t)N * 4);
  int* ssrc           = (int*)carve((size_t)E * 4);
  int* bsum           = (int*)carve(1024);
  int* bpre           = (int*)carve(1024);

  k_zero<<<(N + 255) / 256, 256, 0, stream>>>(deg, N);
  k_zero<<<(N + 255) / 256, 256, 0, stream>>>(cur, N);

  int totW = L * 512 * 512;
  k_prep_w<<<(totW + 255) / 256, 256, 0, stream>>>(gW, Wt, totW);
  k_expand<<<2048, 256, 0, stream>>>(x, eW, eb, h0, N);
  k_deg<<<(E + 255) / 256, 256, 0, stream>>>(dst, deg, E);
  k_dinv<<<(N + 255) / 256, 256, 0, stream>>>(deg, dinv, selfn, N);
  int nb = (N + 1023) / 1024;
  k_scan_a<<<nb, 256, 0, stream>>>(deg, off, bsum, N);
  k_scan_b<<<1, 256, 0, stream>>>(bsum, bpre, nb, off, N, E);
  k_scan_c<<<(N + 255) / 256, 256, 0, stream>>>(off, bpre, N);
  k_fill<<<(E + 255) / 256, 256, 0, stream>>>(src, dst, off, cur, ssrc, E);

  ushort_t* hb[2] = {h0, h1};
  dim3 fgrid((N + 63) / 64);
  for (int l = 0; l < L; ++l) {
    k_fused<<<fgrid, 1024, 0, stream>>>(hb[l & 1], hb[(l & 1) ^ 1],
                                        Wt + (size_t)l * 512 * 512,
                                        gb + (size_t)l * 512,
                                        off, ssrc, dinv, selfn, N);
  }
  k_pool<<<G, 256, 0, stream>>>(hb[L & 1], batch, out, N);
}